// Round 5
// baseline (290.253 us; speedup 1.0000x reference)
//
#include <hip/hip_runtime.h>

typedef _Float16 half8 __attribute__((ext_vector_type(8)));
typedef _Float16 half4 __attribute__((ext_vector_type(4)));
typedef _Float16 half2v __attribute__((ext_vector_type(2)));
typedef float floatx4 __attribute__((ext_vector_type(4)));
typedef float floatx2 __attribute__((ext_vector_type(2)));

#define MFMA_F16 __builtin_amdgcn_mfma_f32_16x16x32_f16
#define FREQ (-0.41524101186092f)   // -log2(10000)/32

static __device__ __forceinline__ unsigned pack_f16(float a, float b) {
    half2v h; h.x = (_Float16)a; h.y = (_Float16)b;   // RTE converts + pack
    return __builtin_bit_cast(unsigned, h);
}

// B=2,H=16,L=8192,D=64,WINDOW=512. Grid 1024 x 512 threads.
// Block = half-window (256 q rows), 8 waves x 32 q-rows each.
// Swapped QK^T (split-K layout): softmax fully in-register, no LDS P buffer.
// 64-key chunks = two verified 32-key sub-tiles per barrier: 8 barriers
// instead of 16, 2x prefetch slack per HBM issue->consume pair.
__global__ __launch_bounds__(512, 4) void swa7(
    const float* __restrict__ Q, const float* __restrict__ K,
    const float* __restrict__ V, const int* __restrict__ pid,
    float* __restrict__ Out)
{
    __shared__ __align__(16) _Float16 lq[128 * 72];          // Q rope staging (2 rounds)
    __shared__ __align__(16) _Float16 lk[2][2][32 * 64];     // roped K, XOR-swizzled, dbuf x sub
    __shared__ __align__(16) _Float16 lvt[2][2][64 * 32];    // V^T, XOR-swizzled, dbuf x sub

    const int bid   = blockIdx.x;
    const int half_ = (bid >> 3) & 1;                     // which half-window
    const int win   = (bid & 7) | ((bid >> 4) << 3);      // 0..511
    const int n = win & 15, bh = win >> 4;
    const long long winrow = (long long)bh * 8192 + n * 512;
    const long long qbase  = winrow + half_ * 256;
    const float* Qb = Q + qbase * 64;
    const float* Kb = K + winrow * 64;
    const float* Vb = V + winrow * 64;
    float* Ob = Out + qbase * 64;
    const int pidq = n * 512 + half_ * 256;
    const int pidk = n * 512;

    const int tid = threadIdx.x, lane = tid & 63, wv = tid >> 6;  // wv 0..7
    const int l15 = lane & 15, quad = (lane >> 4) & 3;
    const float CS = 0.125f * 1.44269504088896f;          // 1/sqrt(D)*log2(e)

    // ---------- Q fragments: 2 rounds of 128 rows through lq ----------
    half8 qf[2][2];
    {
        const int rowl = tid >> 2;          // 0..127 within round
        const int dq   = (tid & 3) * 8;     // pair-dim start
        float ifq[8];
        #pragma unroll
        for (int i = 0; i < 8; ++i) ifq[i] = __builtin_exp2f((float)(dq + i) * FREQ);
        for (int rnd = 0; rnd < 2; ++rnd) {
            const float* src = Qb + (rnd * 128 + rowl) * 64;
            float pos = (float)pid[pidq + rnd * 128 + rowl];
            float4 a0 = *(const float4*)(src + dq);
            float4 a1 = *(const float4*)(src + dq + 4);
            float4 b0 = *(const float4*)(src + 32 + dq);
            float4 b1 = *(const float4*)(src + 36 + dq);
            float lo[8] = {a0.x,a0.y,a0.z,a0.w,a1.x,a1.y,a1.z,a1.w};
            float hi[8] = {b0.x,b0.y,b0.z,b0.w,b1.x,b1.y,b1.z,b1.w};
            half8 wlo, whi;
            #pragma unroll
            for (int i = 0; i < 8; ++i) {
                float sn, cn;
                __sincosf(pos * ifq[i], &sn, &cn);
                wlo[i] = (_Float16)((lo[i] * cn - hi[i] * sn) * CS);
                whi[i] = (_Float16)((hi[i] * cn + lo[i] * sn) * CS);
            }
            if (rnd) __syncthreads();       // round-0 frag reads done
            *(half8*)&lq[rowl * 72 + dq]      = wlo;
            *(half8*)&lq[rowl * 72 + 32 + dq] = whi;
            __syncthreads();
            if ((wv >> 2) == rnd) {
                const int rb = (wv & 3) * 32;
                #pragma unroll
                for (int rt = 0; rt < 2; ++rt) {
                    qf[rt][0] = *(const half8*)&lq[(rb + rt * 16 + l15) * 72 + quad * 8];
                    qf[rt][1] = *(const half8*)&lq[(rb + rt * 16 + l15) * 72 + 32 + quad * 8];
                }
            }
        }
    }

    floatx4 o[2][4], ol[2];
    #pragma unroll
    for (int rt = 0; rt < 2; ++rt) {
        ol[rt] = (floatx4){0.f, 0.f, 0.f, 0.f};
        #pragma unroll
        for (int vt = 0; vt < 4; ++vt) o[rt][vt] = (floatx4){0.f, 0.f, 0.f, 0.f};
    }
    half8 onesf;
    #pragma unroll
    for (int i = 0; i < 8; ++i) onesf[i] = (_Float16)1.0f;

    // staging roles (512 threads); per 64-key chunk each thread handles one
    // key-row / V-key-group in EACH of the two 32-key sub-tiles.
    const int key = tid >> 4;            // 0..31 (K rope: one key/sub, 2 dim-pairs)
    const int pr  = tid & 15;            // pair group: dims 2*pr, 2*pr+1
    const int dv  = tid & 63;            // V gather column
    const int grp = tid >> 6;            // 0..7 -> V keys grp*4..grp*4+3 (per sub)
    float if2[2];
    #pragma unroll
    for (int i = 0; i < 2; ++i) if2[i] = __builtin_exp2f((float)(pr * 2 + i) * FREQ);
    const int klo_addr = key * 64 + (((pr >> 2) ^ (key & 7)) * 8) + (pr & 3) * 2;
    const int khi_addr = key * 64 + ((((pr >> 2) + 4) ^ (key & 7)) * 8) + (pr & 3) * 2;
    // V store: key-group g=grp at octet slot (g&3)^swz, sub-slot (g>>2)*4.
    // b128 read at octet quad yields [keys 4q..4q+3 | keys 16+4q..19+4q].
    const int vst_addr = dv * 32 + (((grp & 3) ^ ((dv >> 1) & 3)) * 8) + (grp >> 2) * 4;
    const int ksw0 = (quad ^ (l15 & 7)) * 8;
    const int ksw1 = ((quad + 4) ^ (l15 & 7)) * 8;
    const int vsw  = (quad ^ ((l15 >> 1) & 3)) * 8;

    // prologue: prefetch chunk 0 (both 32-key sub-tiles)
    floatx2 ka[2], kb[2];
    float vr[2][4];
    int kp[2];
    #pragma unroll
    for (int s = 0; s < 2; ++s) {
        const float* ks = Kb + s * 2048;
        const float* vs = Vb + s * 2048;
        ka[s] = *(const floatx2*)(ks + key * 64 + pr * 2);
        kb[s] = *(const floatx2*)(ks + key * 64 + 32 + pr * 2);
        #pragma unroll
        for (int i = 0; i < 4; ++i) vr[s][i] = vs[(grp * 4 + i) * 64 + dv];
        kp[s] = pid[pidk + s * 32 + key];
    }

    for (int kc = 0; kc < 8; ++kc) {
        const int cur = kc & 1;
        // rope K regs -> f16 and stage both sub-tiles
        #pragma unroll
        for (int s = 0; s < 2; ++s) {
            float kpos = (float)kp[s];
            half2v klo, khi;
            {
                float a[2] = {ka[s].x, ka[s].y};
                float b[2] = {kb[s].x, kb[s].y};
                #pragma unroll
                for (int i = 0; i < 2; ++i) {
                    float sn, cn;
                    __sincosf(kpos * if2[i], &sn, &cn);
                    klo[i] = (_Float16)(a[i] * cn - b[i] * sn);
                    khi[i] = (_Float16)(b[i] * cn + a[i] * sn);
                }
            }
            half4 vh;
            #pragma unroll
            for (int i = 0; i < 4; ++i) vh[i] = (_Float16)vr[s][i];
            *(half2v*)&lk[cur][s][klo_addr] = klo;
            *(half2v*)&lk[cur][s][khi_addr] = khi;
            *(half4*)&lvt[cur][s][vst_addr] = vh;
        }
        __syncthreads();                  // writes of buf[cur] visible; prev buf reads done

        // prefetch next 64-key chunk while computing this one
        if (kc < 7) {
            #pragma unroll
            for (int s = 0; s < 2; ++s) {
                const float* kn = Kb + (kc + 1) * 4096 + s * 2048;
                const float* vn = Vb + (kc + 1) * 4096 + s * 2048;
                ka[s] = *(const floatx2*)(kn + key * 64 + pr * 2);
                kb[s] = *(const floatx2*)(kn + key * 64 + 32 + pr * 2);
                #pragma unroll
                for (int i = 0; i < 4; ++i) vr[s][i] = vn[(grp * 4 + i) * 64 + dv];
                kp[s] = pid[pidk + (kc + 1) * 64 + s * 32 + key];
            }
        }

        // compute both sub-tiles (each identical to the verified 32-key body)
        #pragma unroll
        for (int s = 0; s < 2; ++s) {
            half8 kf00 = *(const half8*)&lk[cur][s][l15 * 64 + ksw0];
            half8 kf01 = *(const half8*)&lk[cur][s][l15 * 64 + ksw1];
            half8 kf10 = *(const half8*)&lk[cur][s][(16 + l15) * 64 + ksw0];
            half8 kf11 = *(const half8*)&lk[cur][s][(16 + l15) * 64 + ksw1];
            half8 vf[4];
            #pragma unroll
            for (int vt = 0; vt < 4; ++vt)
                vf[vt] = *(const half8*)&lvt[cur][s][(vt * 16 + l15) * 32 + vsw];

            __builtin_amdgcn_s_setprio(1);
            #pragma unroll
            for (int rt = 0; rt < 2; ++rt) {
                // swapped operands: lane holds S^T[key=quad*4+r][q=l15]
                floatx4 s0 = {0.f,0.f,0.f,0.f}, s1 = {0.f,0.f,0.f,0.f};
                s0 = MFMA_F16(kf00, qf[rt][0], s0, 0, 0, 0);
                s0 = MFMA_F16(kf01, qf[rt][1], s0, 0, 0, 0);
                s1 = MFMA_F16(kf10, qf[rt][0], s1, 0, 0, 0);
                s1 = MFMA_F16(kf11, qf[rt][1], s1, 0, 0, 0);

                // split-K A-layout: elems 0-3 -> k=quad*4+i, 4-7 -> k=16+quad*4+i
                // = exactly this lane's own s0/s1 -> no cross-lane movement.
                union { unsigned u[4]; half8 h; } pfu;
                pfu.u[0] = pack_f16(__builtin_exp2f(s0[0]), __builtin_exp2f(s0[1]));
                pfu.u[1] = pack_f16(__builtin_exp2f(s0[2]), __builtin_exp2f(s0[3]));
                pfu.u[2] = pack_f16(__builtin_exp2f(s1[0]), __builtin_exp2f(s1[1]));
                pfu.u[3] = pack_f16(__builtin_exp2f(s1[2]), __builtin_exp2f(s1[3]));
                half8 pf = pfu.h;

                ol[rt] = MFMA_F16(pf, onesf, ol[rt], 0, 0, 0);
                #pragma unroll
                for (int vt = 0; vt < 4; ++vt)
                    o[rt][vt] = MFMA_F16(pf, vf[vt], o[rt][vt], 0, 0, 0);
            }
            __builtin_amdgcn_s_setprio(0);
        }
    }

    // ---------- epilogue ----------
    #pragma unroll
    for (int rt = 0; rt < 2; ++rt) {
        #pragma unroll
        for (int r = 0; r < 4; ++r) {
            int rowl = wv * 32 + rt * 16 + quad * 4 + r;   // 0..255
            int j = half_ * 256 + rowl;                    // row within window
            float w;
            if (n == 0 || n == 15)  w = 1.0f;
            else if (j < 64)        w = (float)j * (1.0f / 63.0f);
            else if (j >= 448)      w = (float)(511 - j) * (1.0f / 63.0f);
            else                    w = 1.0f;
            float f = (w / (w + 1e-8f)) / ol[rt][r];
            #pragma unroll
            for (int vt = 0; vt < 4; ++vt)
                Ob[rowl * 64 + vt * 16 + l15] = o[rt][vt][r] * f;
        }
    }
}

extern "C" void kernel_launch(void* const* d_in, const int* in_sizes, int n_in,
                              void* d_out, int out_size, void* d_ws, size_t ws_size,
                              hipStream_t stream) {
    const float* q   = (const float*)d_in[0];
    const float* k   = (const float*)d_in[1];
    const float* v   = (const float*)d_in[2];
    const int*   pid = (const int*)d_in[3];
    float* out = (float*)d_out;
    (void)in_sizes; (void)n_in; (void)out_size; (void)d_ws; (void)ws_size;
    swa7<<<dim3(1024), dim3(512), 0, stream>>>(q, k, v, pid, out);
}

// Round 6
// 280.220 us; speedup vs baseline: 1.0358x; 1.0358x over previous
//
#include <hip/hip_runtime.h>

typedef _Float16 half8 __attribute__((ext_vector_type(8)));
typedef _Float16 half4 __attribute__((ext_vector_type(4)));
typedef _Float16 half2v __attribute__((ext_vector_type(2)));
typedef float floatx4 __attribute__((ext_vector_type(4)));

#define MFMA_F16 __builtin_amdgcn_mfma_f32_16x16x32_f16
#define FREQ (-0.41524101186092f)   // -log2(10000)/32

static __device__ __forceinline__ unsigned pack_f16(float a, float b) {
    half2v h; h.x = (_Float16)a; h.y = (_Float16)b;   // RTE converts + pack
    return __builtin_bit_cast(unsigned, h);
}

// B=2,H=16,L=8192,D=64,WINDOW=512. Grid 2048 x 256 threads.
// Block = quarter-window (128 q rows), 4 waves x 32 q-rows each.
// Same verified per-wave body as swa6 (split-K in-register softmax, 32-key
// chunks, 16 barriers) but 4-wave barrier domains and 4 independent
// blocks/CU: when one block waits at barrier/vmcnt, three others issue.
// Window's 4 blocks share XCD (bid%8 invariant) for K/V L2 reuse.
__global__ __launch_bounds__(256, 4) void swa8(
    const float* __restrict__ Q, const float* __restrict__ K,
    const float* __restrict__ V, const int* __restrict__ pid,
    float* __restrict__ Out)
{
    __shared__ __align__(16) _Float16 lq[64 * 72];        // Q rope staging (2 rounds x 64 rows)
    __shared__ __align__(16) _Float16 lk[2][32 * 64];     // roped K chunk, XOR-swizzled, dbuf
    __shared__ __align__(16) _Float16 lvt[2][64 * 32];    // V^T chunk, XOR-swizzled, dbuf

    const int bid     = blockIdx.x;
    const int quarter = (bid >> 3) & 3;                   // quarter-window
    const int win     = (bid & 7) | ((bid >> 5) << 3);    // 0..511
    const int n = win & 15, bh = win >> 4;
    const long long winrow = (long long)bh * 8192 + n * 512;
    const long long qbase  = winrow + quarter * 128;
    const float* Qb = Q + qbase * 64;
    const float* Kb = K + winrow * 64;
    const float* Vb = V + winrow * 64;
    float* Ob = Out + qbase * 64;
    const int pidq = n * 512 + quarter * 128;
    const int pidk = n * 512;

    const int tid = threadIdx.x, lane = tid & 63, wv = tid >> 6;  // wv 0..3
    const int l15 = lane & 15, quad = (lane >> 4) & 3;
    const float CS = 0.125f * 1.44269504088896f;          // 1/sqrt(D)*log2(e)

    // ---------- Q fragments: 2 rounds of 64 rows through lq ----------
    half8 qf[2][2];
    {
        const int rowl = tid >> 2;          // 0..63 within round
        const int dq   = (tid & 3) * 8;     // pair-dim start
        float ifq[8];
        #pragma unroll
        for (int i = 0; i < 8; ++i) ifq[i] = __builtin_exp2f((float)(dq + i) * FREQ);
        for (int rnd = 0; rnd < 2; ++rnd) {
            const float* src = Qb + (rnd * 64 + rowl) * 64;
            float pos = (float)pid[pidq + rnd * 64 + rowl];
            float4 a0 = *(const float4*)(src + dq);
            float4 a1 = *(const float4*)(src + dq + 4);
            float4 b0 = *(const float4*)(src + 32 + dq);
            float4 b1 = *(const float4*)(src + 36 + dq);
            float lo[8] = {a0.x,a0.y,a0.z,a0.w,a1.x,a1.y,a1.z,a1.w};
            float hi[8] = {b0.x,b0.y,b0.z,b0.w,b1.x,b1.y,b1.z,b1.w};
            half8 wlo, whi;
            #pragma unroll
            for (int i = 0; i < 8; ++i) {
                float sn, cn;
                __sincosf(pos * ifq[i], &sn, &cn);
                wlo[i] = (_Float16)((lo[i] * cn - hi[i] * sn) * CS);
                whi[i] = (_Float16)((hi[i] * cn + lo[i] * sn) * CS);
            }
            if (rnd) __syncthreads();       // round-0 frag reads done
            *(half8*)&lq[rowl * 72 + dq]      = wlo;
            *(half8*)&lq[rowl * 72 + 32 + dq] = whi;
            __syncthreads();
            if ((wv >> 1) == rnd) {         // waves 0,1 read round 0; 2,3 round 1
                const int rb = (wv & 1) * 32;
                #pragma unroll
                for (int rt = 0; rt < 2; ++rt) {
                    qf[rt][0] = *(const half8*)&lq[(rb + rt * 16 + l15) * 72 + quad * 8];
                    qf[rt][1] = *(const half8*)&lq[(rb + rt * 16 + l15) * 72 + 32 + quad * 8];
                }
            }
        }
    }

    floatx4 o[2][4], ol[2];
    #pragma unroll
    for (int rt = 0; rt < 2; ++rt) {
        ol[rt] = (floatx4){0.f, 0.f, 0.f, 0.f};
        #pragma unroll
        for (int vt = 0; vt < 4; ++vt) o[rt][vt] = (floatx4){0.f, 0.f, 0.f, 0.f};
    }
    half8 onesf;
    #pragma unroll
    for (int i = 0; i < 8; ++i) onesf[i] = (_Float16)1.0f;

    // staging roles (256 threads)
    const int key = tid >> 3;            // 0..31 (K rope: one key, 4 dim-pairs)
    const int d0  = (tid & 7) * 4;       // dims d0..d0+3 paired with d0+32..
    const int dv  = tid & 63;            // V gather column
    const int k8  = tid >> 6;            // 0..3 -> V keys k8*8..k8*8+7
    float if4[4];
    #pragma unroll
    for (int i = 0; i < 4; ++i) if4[i] = __builtin_exp2f((float)(d0 + i) * FREQ);
    const int klo_addr = key * 64 + (((d0 >> 3) ^ (key & 7)) * 8) + (d0 & 7);
    const int khi_addr = key * 64 + ((((d0 >> 3) + 4) ^ (key & 7)) * 8) + (d0 & 7);
    // V split-K layout (verified r4): group g (keys 4g..4g+3) at octet slot
    // (g&3)^swz, sub-slot (g>>2)*4. Thread covers g = 2*k8 and 2*k8+1.
    int vst_addr[2];
    #pragma unroll
    for (int h = 0; h < 2; ++h) {
        int g = 2 * k8 + h;
        vst_addr[h] = dv * 32 + (((g & 3) ^ ((dv >> 1) & 3)) * 8) + ((g >> 2) * 4);
    }
    const int ksw0 = (quad ^ (l15 & 7)) * 8;
    const int ksw1 = ((quad + 4) ^ (l15 & 7)) * 8;
    const int vsw  = (quad ^ ((l15 >> 1) & 3)) * 8;

    // prologue: prefetch chunk 0
    float4 ka  = *(const float4*)(Kb + key * 64 + d0);
    float4 kb2 = *(const float4*)(Kb + key * 64 + 32 + d0);
    float vr[8];
    #pragma unroll
    for (int i = 0; i < 8; ++i) vr[i] = Vb[(k8 * 8 + i) * 64 + dv];
    int kp = pid[pidk + key];

    for (int kc = 0; kc < 16; ++kc) {
        const int cur = kc & 1;
        // rope K regs -> f16
        float kpos = (float)kp;
        half4 klo, khi;
        {
            float a[4] = {ka.x, ka.y, ka.z, ka.w};
            float b[4] = {kb2.x, kb2.y, kb2.z, kb2.w};
            #pragma unroll
            for (int i = 0; i < 4; ++i) {
                float sn, cn;
                __sincosf(kpos * if4[i], &sn, &cn);
                klo[i] = (_Float16)(a[i] * cn - b[i] * sn);
                khi[i] = (_Float16)(b[i] * cn + a[i] * sn);
            }
        }
        half4 vh0, vh1;
        #pragma unroll
        for (int i = 0; i < 4; ++i) { vh0[i] = (_Float16)vr[i]; vh1[i] = (_Float16)vr[4 + i]; }

        *(half4*)&lk[cur][klo_addr] = klo;
        *(half4*)&lk[cur][khi_addr] = khi;
        *(half4*)&lvt[cur][vst_addr[0]] = vh0;
        *(half4*)&lvt[cur][vst_addr[1]] = vh1;
        __syncthreads();                  // writes of buf[cur] visible; prev buf reads done

        // prefetch next chunk while computing this one
        if (kc < 15) {
            const float* kn = Kb + (kc + 1) * 2048;
            const float* vn = Vb + (kc + 1) * 2048;
            ka  = *(const float4*)(kn + key * 64 + d0);
            kb2 = *(const float4*)(kn + key * 64 + 32 + d0);
            #pragma unroll
            for (int i = 0; i < 8; ++i) vr[i] = vn[(k8 * 8 + i) * 64 + dv];
            kp = pid[pidk + (kc + 1) * 32 + key];
        }

        // fragments (verified layouts, unchanged)
        half8 kf00 = *(const half8*)&lk[cur][l15 * 64 + ksw0];
        half8 kf01 = *(const half8*)&lk[cur][l15 * 64 + ksw1];
        half8 kf10 = *(const half8*)&lk[cur][(16 + l15) * 64 + ksw0];
        half8 kf11 = *(const half8*)&lk[cur][(16 + l15) * 64 + ksw1];
        half8 vf[4];
        #pragma unroll
        for (int vt = 0; vt < 4; ++vt)
            vf[vt] = *(const half8*)&lvt[cur][(vt * 16 + l15) * 32 + vsw];

        __builtin_amdgcn_s_setprio(1);
        #pragma unroll
        for (int rt = 0; rt < 2; ++rt) {
            // swapped operands: lane holds S^T[key=quad*4+r][q=l15]
            floatx4 s0 = {0.f,0.f,0.f,0.f}, s1 = {0.f,0.f,0.f,0.f};
            s0 = MFMA_F16(kf00, qf[rt][0], s0, 0, 0, 0);
            s0 = MFMA_F16(kf01, qf[rt][1], s0, 0, 0, 0);
            s1 = MFMA_F16(kf10, qf[rt][0], s1, 0, 0, 0);
            s1 = MFMA_F16(kf11, qf[rt][1], s1, 0, 0, 0);

            // split-K A-layout: elems 0-3 -> k=quad*4+i, 4-7 -> k=16+quad*4+i
            // = exactly this lane's own s0/s1 -> no cross-lane movement.
            union { unsigned u[4]; half8 h; } pfu;
            pfu.u[0] = pack_f16(__builtin_exp2f(s0[0]), __builtin_exp2f(s0[1]));
            pfu.u[1] = pack_f16(__builtin_exp2f(s0[2]), __builtin_exp2f(s0[3]));
            pfu.u[2] = pack_f16(__builtin_exp2f(s1[0]), __builtin_exp2f(s1[1]));
            pfu.u[3] = pack_f16(__builtin_exp2f(s1[2]), __builtin_exp2f(s1[3]));
            half8 pf = pfu.h;

            ol[rt] = MFMA_F16(pf, onesf, ol[rt], 0, 0, 0);
            #pragma unroll
            for (int vt = 0; vt < 4; ++vt)
                o[rt][vt] = MFMA_F16(pf, vf[vt], o[rt][vt], 0, 0, 0);
        }
        __builtin_amdgcn_s_setprio(0);
    }

    // ---------- epilogue ----------
    #pragma unroll
    for (int rt = 0; rt < 2; ++rt) {
        #pragma unroll
        for (int r = 0; r < 4; ++r) {
            int rowl = wv * 32 + rt * 16 + quad * 4 + r;   // 0..127
            int j = quarter * 128 + rowl;                  // row within window
            float w;
            if (n == 0 || n == 15)  w = 1.0f;
            else if (j < 64)        w = (float)j * (1.0f / 63.0f);
            else if (j >= 448)      w = (float)(511 - j) * (1.0f / 63.0f);
            else                    w = 1.0f;
            float f = (w / (w + 1e-8f)) / ol[rt][r];
            #pragma unroll
            for (int vt = 0; vt < 4; ++vt)
                Ob[rowl * 64 + vt * 16 + l15] = o[rt][vt][r] * f;
        }
    }
}

extern "C" void kernel_launch(void* const* d_in, const int* in_sizes, int n_in,
                              void* d_out, int out_size, void* d_ws, size_t ws_size,
                              hipStream_t stream) {
    const float* q   = (const float*)d_in[0];
    const float* k   = (const float*)d_in[1];
    const float* v   = (const float*)d_in[2];
    const int*   pid = (const int*)d_in[3];
    float* out = (float*)d_out;
    (void)in_sizes; (void)n_in; (void)out_size; (void)d_ws; (void)ws_size;
    swa8<<<dim3(2048), dim3(256), 0, stream>>>(q, k, v, pid, out);
}

// Round 7
// 233.682 us; speedup vs baseline: 1.2421x; 1.1992x over previous
//
#include <hip/hip_runtime.h>

typedef _Float16 half8 __attribute__((ext_vector_type(8)));
typedef _Float16 half4 __attribute__((ext_vector_type(4)));
typedef _Float16 half2v __attribute__((ext_vector_type(2)));
typedef float floatx4 __attribute__((ext_vector_type(4)));
typedef float floatx2 __attribute__((ext_vector_type(2)));

#define MFMA_F16 __builtin_amdgcn_mfma_f32_16x16x32_f16
#define FREQ (-0.41524101186092f)        // -log2(10000)/32
#define INV2PI 0.15915494309189535f      // 1/(2*pi)

static __device__ __forceinline__ unsigned pack_f16(float a, float b) {
    half2v h; h.x = (_Float16)a; h.y = (_Float16)b;   // RTE converts + pack
    return __builtin_bit_cast(unsigned, h);
}

// hardware trig: angle given in REVOLUTIONS (pos * freq/2pi).
// v_fract + v_sin/v_cos: ~5 insts vs ~70 for __ocml_sincos large-arg path.
static __device__ __forceinline__ void hw_sincos(float rev, float* sn, float* cn) {
    float f = __builtin_amdgcn_fractf(rev);
    *sn = __builtin_amdgcn_sinf(f);      // sin(2*pi*f)
    *cn = __builtin_amdgcn_cosf(f);      // cos(2*pi*f)
}

// B=2,H=16,L=8192,D=64,WINDOW=512. Grid 1024 x 512 threads.
// Block = half-window (256 q rows), 8 waves x 32 q-rows each.
// Swapped QK^T (split-K layout): softmax fully in-register, no LDS P buffer.
// RoPE via hardware v_sin/v_cos in revolution units (the round-6 finding:
// __sincosf's large-arg ocml path was ~6x the expected VALU work).
__global__ __launch_bounds__(512, 4) void swa9(
    const float* __restrict__ Q, const float* __restrict__ K,
    const float* __restrict__ V, const int* __restrict__ pid,
    float* __restrict__ Out)
{
    __shared__ __align__(16) _Float16 lq[128 * 72];       // Q rope staging (2 rounds)
    __shared__ __align__(16) _Float16 lk[2][32 * 64];     // roped K chunk, XOR-swizzled, dbuf
    __shared__ __align__(16) _Float16 lvt[2][64 * 32];    // V^T chunk, XOR-swizzled, dbuf

    const int bid   = blockIdx.x;
    const int half_ = (bid >> 3) & 1;                     // which half-window
    const int win   = (bid & 7) | ((bid >> 4) << 3);      // 0..511
    const int n = win & 15, bh = win >> 4;
    const long long winrow = (long long)bh * 8192 + n * 512;
    const long long qbase  = winrow + half_ * 256;
    const float* Qb = Q + qbase * 64;
    const float* Kb = K + winrow * 64;
    const float* Vb = V + winrow * 64;
    float* Ob = Out + qbase * 64;
    const int pidq = n * 512 + half_ * 256;
    const int pidk = n * 512;

    const int tid = threadIdx.x, lane = tid & 63, wv = tid >> 6;  // wv 0..7
    const int l15 = lane & 15, quad = (lane >> 4) & 3;
    const float CS = 0.125f * 1.44269504088896f;          // 1/sqrt(D)*log2(e)

    // ---------- Q fragments: 2 rounds of 128 rows through lq ----------
    half8 qf[2][2];
    {
        const int rowl = tid >> 2;          // 0..127 within round
        const int dq   = (tid & 3) * 8;     // pair-dim start
        float ifq[8];                        // freq / 2pi (revolution units)
        #pragma unroll
        for (int i = 0; i < 8; ++i)
            ifq[i] = __builtin_exp2f((float)(dq + i) * FREQ) * INV2PI;
        for (int rnd = 0; rnd < 2; ++rnd) {
            const float* src = Qb + (rnd * 128 + rowl) * 64;
            float pos = (float)pid[pidq + rnd * 128 + rowl];
            float4 a0 = *(const float4*)(src + dq);
            float4 a1 = *(const float4*)(src + dq + 4);
            float4 b0 = *(const float4*)(src + 32 + dq);
            float4 b1 = *(const float4*)(src + 36 + dq);
            float lo[8] = {a0.x,a0.y,a0.z,a0.w,a1.x,a1.y,a1.z,a1.w};
            float hi[8] = {b0.x,b0.y,b0.z,b0.w,b1.x,b1.y,b1.z,b1.w};
            half8 wlo, whi;
            #pragma unroll
            for (int i = 0; i < 8; ++i) {
                float sn, cn;
                hw_sincos(pos * ifq[i], &sn, &cn);
                wlo[i] = (_Float16)((lo[i] * cn - hi[i] * sn) * CS);
                whi[i] = (_Float16)((hi[i] * cn + lo[i] * sn) * CS);
            }
            if (rnd) __syncthreads();       // round-0 frag reads done
            *(half8*)&lq[rowl * 72 + dq]      = wlo;
            *(half8*)&lq[rowl * 72 + 32 + dq] = whi;
            __syncthreads();
            if ((wv >> 2) == rnd) {
                const int rb = (wv & 3) * 32;
                #pragma unroll
                for (int rt = 0; rt < 2; ++rt) {
                    qf[rt][0] = *(const half8*)&lq[(rb + rt * 16 + l15) * 72 + quad * 8];
                    qf[rt][1] = *(const half8*)&lq[(rb + rt * 16 + l15) * 72 + 32 + quad * 8];
                }
            }
        }
    }

    floatx4 o[2][4], ol[2];
    #pragma unroll
    for (int rt = 0; rt < 2; ++rt) {
        ol[rt] = (floatx4){0.f, 0.f, 0.f, 0.f};
        #pragma unroll
        for (int vt = 0; vt < 4; ++vt) o[rt][vt] = (floatx4){0.f, 0.f, 0.f, 0.f};
    }
    half8 onesf;
    #pragma unroll
    for (int i = 0; i < 8; ++i) onesf[i] = (_Float16)1.0f;

    // staging roles (512 threads)
    const int key = tid >> 4;            // 0..31 (K rope: one key, 2 dim-pairs)
    const int pr  = tid & 15;            // pair group: dims 2*pr, 2*pr+1
    const int dv  = tid & 63;            // V gather column
    const int grp = tid >> 6;            // 0..7 -> V keys grp*4..grp*4+3
    float if2[2];                        // freq / 2pi
    #pragma unroll
    for (int i = 0; i < 2; ++i)
        if2[i] = __builtin_exp2f((float)(pr * 2 + i) * FREQ) * INV2PI;
    const int klo_addr = key * 64 + (((pr >> 2) ^ (key & 7)) * 8) + (pr & 3) * 2;
    const int khi_addr = key * 64 + ((((pr >> 2) + 4) ^ (key & 7)) * 8) + (pr & 3) * 2;
    // V store: key-group g=grp at octet slot (g&3)^swz, sub-slot (g>>2)*4.
    // b128 read at octet quad yields [keys 4q..4q+3 | keys 16+4q..19+4q].
    const int vst_addr = dv * 32 + (((grp & 3) ^ ((dv >> 1) & 3)) * 8) + (grp >> 2) * 4;
    const int ksw0 = (quad ^ (l15 & 7)) * 8;
    const int ksw1 = ((quad + 4) ^ (l15 & 7)) * 8;
    const int vsw  = (quad ^ ((l15 >> 1) & 3)) * 8;

    // prologue: prefetch chunk 0
    floatx2 ka  = *(const floatx2*)(Kb + key * 64 + pr * 2);
    floatx2 kb2 = *(const floatx2*)(Kb + key * 64 + 32 + pr * 2);
    float vr[4];
    #pragma unroll
    for (int i = 0; i < 4; ++i) vr[i] = Vb[(grp * 4 + i) * 64 + dv];
    int kp = pid[pidk + key];

    for (int kc = 0; kc < 16; ++kc) {
        const int cur = kc & 1;
        // rope K regs -> f16
        float kpos = (float)kp;
        half2v klo, khi;
        {
            float a[2] = {ka.x, ka.y};
            float b[2] = {kb2.x, kb2.y};
            #pragma unroll
            for (int i = 0; i < 2; ++i) {
                float sn, cn;
                hw_sincos(kpos * if2[i], &sn, &cn);
                klo[i] = (_Float16)(a[i] * cn - b[i] * sn);
                khi[i] = (_Float16)(b[i] * cn + a[i] * sn);
            }
        }
        half4 vh;
        #pragma unroll
        for (int i = 0; i < 4; ++i) vh[i] = (_Float16)vr[i];

        *(half2v*)&lk[cur][klo_addr] = klo;
        *(half2v*)&lk[cur][khi_addr] = khi;
        *(half4*)&lvt[cur][vst_addr] = vh;
        __syncthreads();                  // writes of buf[cur] visible; prev buf reads done

        // prefetch next chunk while computing this one
        if (kc < 15) {
            const float* kn = Kb + (kc + 1) * 2048;
            const float* vn = Vb + (kc + 1) * 2048;
            ka  = *(const floatx2*)(kn + key * 64 + pr * 2);
            kb2 = *(const floatx2*)(kn + key * 64 + 32 + pr * 2);
            #pragma unroll
            for (int i = 0; i < 4; ++i) vr[i] = vn[(grp * 4 + i) * 64 + dv];
            kp = pid[pidk + (kc + 1) * 32 + key];
        }

        // fragments (shared across row-tiles)
        half8 kf00 = *(const half8*)&lk[cur][l15 * 64 + ksw0];
        half8 kf01 = *(const half8*)&lk[cur][l15 * 64 + ksw1];
        half8 kf10 = *(const half8*)&lk[cur][(16 + l15) * 64 + ksw0];
        half8 kf11 = *(const half8*)&lk[cur][(16 + l15) * 64 + ksw1];
        half8 vf[4];
        #pragma unroll
        for (int vt = 0; vt < 4; ++vt)
            vf[vt] = *(const half8*)&lvt[cur][(vt * 16 + l15) * 32 + vsw];

        __builtin_amdgcn_s_setprio(1);
        #pragma unroll
        for (int rt = 0; rt < 2; ++rt) {
            // swapped operands: lane holds S^T[key=quad*4+r][q=l15]
            floatx4 s0 = {0.f,0.f,0.f,0.f}, s1 = {0.f,0.f,0.f,0.f};
            s0 = MFMA_F16(kf00, qf[rt][0], s0, 0, 0, 0);
            s0 = MFMA_F16(kf01, qf[rt][1], s0, 0, 0, 0);
            s1 = MFMA_F16(kf10, qf[rt][0], s1, 0, 0, 0);
            s1 = MFMA_F16(kf11, qf[rt][1], s1, 0, 0, 0);

            // split-K A-layout: elems 0-3 -> k=quad*4+i, 4-7 -> k=16+quad*4+i
            // = exactly this lane's own s0/s1 -> no cross-lane movement.
            union { unsigned u[4]; half8 h; } pfu;
            pfu.u[0] = pack_f16(__builtin_exp2f(s0[0]), __builtin_exp2f(s0[1]));
            pfu.u[1] = pack_f16(__builtin_exp2f(s0[2]), __builtin_exp2f(s0[3]));
            pfu.u[2] = pack_f16(__builtin_exp2f(s1[0]), __builtin_exp2f(s1[1]));
            pfu.u[3] = pack_f16(__builtin_exp2f(s1[2]), __builtin_exp2f(s1[3]));
            half8 pf = pfu.h;

            ol[rt] = MFMA_F16(pf, onesf, ol[rt], 0, 0, 0);
            #pragma unroll
            for (int vt = 0; vt < 4; ++vt)
                o[rt][vt] = MFMA_F16(pf, vf[vt], o[rt][vt], 0, 0, 0);
        }
        __builtin_amdgcn_s_setprio(0);
    }

    // ---------- epilogue ----------
    #pragma unroll
    for (int rt = 0; rt < 2; ++rt) {
        #pragma unroll
        for (int r = 0; r < 4; ++r) {
            int rowl = wv * 32 + rt * 16 + quad * 4 + r;   // 0..255
            int j = half_ * 256 + rowl;                    // row within window
            float w;
            if (n == 0 || n == 15)  w = 1.0f;
            else if (j < 64)        w = (float)j * (1.0f / 63.0f);
            else if (j >= 448)      w = (float)(511 - j) * (1.0f / 63.0f);
            else                    w = 1.0f;
            float f = (w / (w + 1e-8f)) / ol[rt][r];
            #pragma unroll
            for (int vt = 0; vt < 4; ++vt)
                Ob[rowl * 64 + vt * 16 + l15] = o[rt][vt][r] * f;
        }
    }
}

extern "C" void kernel_launch(void* const* d_in, const int* in_sizes, int n_in,
                              void* d_out, int out_size, void* d_ws, size_t ws_size,
                              hipStream_t stream) {
    const float* q   = (const float*)d_in[0];
    const float* k   = (const float*)d_in[1];
    const float* v   = (const float*)d_in[2];
    const int*   pid = (const int*)d_in[3];
    float* out = (float*)d_out;
    (void)in_sizes; (void)n_in; (void)out_size; (void)d_ws; (void)ws_size;
    swa9<<<dim3(1024), dim3(512), 0, stream>>>(q, k, v, pid, out);
}